// Round 2
// baseline (38041.620 us; speedup 1.0000x reference)
//
#include <hip/hip_runtime.h>
#include <hip/hip_bf16.h>

#define BB 256
#define TT 1024
#define DIN 64
#define HH 1024
#define NL 3
#define ALPHA 0.5f

typedef __attribute__((ext_vector_type(8))) short bf16x8;
typedef __attribute__((ext_vector_type(4))) float f32x4;
typedef __attribute__((ext_vector_type(4))) unsigned short u16x4;

// ---- workspace byte offsets ----
// xT  : bf16 [T][B][DIN]                      size 33,554,432
// Wb  : bf16 [win0|win1|win2|wres0|wres1|wres2] size 10,616,832
// S16 : bf16 [2][NL][B][H]                    size  3,145,728
// S32 : f32  [NL][B][H]                       size  3,145,728
static const size_t XT_OFF  = 0;
static const size_t WB_OFF  = 33554432;
static const size_t S16_OFF = 44171264;
static const size_t S32_OFF = 47316992;

// element offsets inside Wb (bf16 elements)
#define WIN0_E   0          // [H][DIN]
#define WIN12_E  65536      // win1, win2: each [H][H]
#define WRES_E   2162688    // wres0..2: each [H][H]

// ---------------- weight fp32 -> bf16 convert ----------------
__global__ void convert_kernel(const float* __restrict__ w_in0,
                               const float* __restrict__ w_in_rest,
                               const float* __restrict__ w_res,
                               __hip_bfloat16* __restrict__ Wb)
{
    const size_t total = 65536ull + 2097152ull + 3145728ull; // 5,308,416
    for (size_t i = (size_t)blockIdx.x * blockDim.x + threadIdx.x; i < total;
         i += (size_t)gridDim.x * blockDim.x) {
        float v;
        if (i < 65536)            v = w_in0[i];
        else if (i < 2162688)     v = w_in_rest[i - 65536];
        else                      v = w_res[i - 2162688];
        Wb[i] = __float2bfloat16(v);
    }
}

// ---------------- x [B][T][D] fp32 -> xT [T][B][D] bf16 ----------------
__global__ void transpose_x_kernel(const float* __restrict__ x,
                                   unsigned short* __restrict__ xT)
{
    const size_t n4 = (size_t)BB * TT * DIN / 4; // 4,194,304 float4s
    for (size_t i = (size_t)blockIdx.x * blockDim.x + threadIdx.x; i < n4;
         i += (size_t)gridDim.x * blockDim.x) {
        size_t flat = i * 4;
        int d = (int)(flat & (DIN - 1));
        int t = (int)((flat >> 6) & (TT - 1));
        int b = (int)(flat >> 16);
        const float4 v = reinterpret_cast<const float4*>(x)[i];
        __hip_bfloat16 h0 = __float2bfloat16(v.x);
        __hip_bfloat16 h1 = __float2bfloat16(v.y);
        __hip_bfloat16 h2 = __float2bfloat16(v.z);
        __hip_bfloat16 h3 = __float2bfloat16(v.w);
        u16x4 pk;
        pk.x = *(unsigned short*)&h0; pk.y = *(unsigned short*)&h1;
        pk.z = *(unsigned short*)&h2; pk.w = *(unsigned short*)&h3;
        *reinterpret_cast<u16x4*>(xT + ((size_t)t * BB + b) * DIN + d) = pk;
    }
}

// ---------------- MFMA inner loop ----------------
template <int K>
__device__ __forceinline__ void gemm_part(const unsigned short* __restrict__ Ar,
                                          const unsigned short* __restrict__ Ar2,
                                          const unsigned short* __restrict__ Br,
                                          const unsigned short* __restrict__ Br2,
                                          f32x4& a00, f32x4& a01, f32x4& a10, f32x4& a11)
{
#pragma unroll 4
    for (int k = 0; k < K; k += 32) {
        bf16x8 a0 = *reinterpret_cast<const bf16x8*>(Ar + k);
        bf16x8 a1 = *reinterpret_cast<const bf16x8*>(Ar2 + k);
        bf16x8 b0 = *reinterpret_cast<const bf16x8*>(Br + k);
        bf16x8 b1 = *reinterpret_cast<const bf16x8*>(Br2 + k);
        a00 = __builtin_amdgcn_mfma_f32_16x16x32_bf16(a0, b0, a00, 0, 0, 0);
        a01 = __builtin_amdgcn_mfma_f32_16x16x32_bf16(a0, b1, a01, 0, 0, 0);
        a10 = __builtin_amdgcn_mfma_f32_16x16x32_bf16(a1, b0, a10, 0, 0, 0);
        a11 = __builtin_amdgcn_mfma_f32_16x16x32_bf16(a1, b1, a11, 0, 0, 0);
    }
}

// ---------------- one wavefront super-step ----------------
// grid: 192 wgs = 4 batch-tiles (Mt=64) x 48 flat row-tiles (3 layers x 16 tiles of 64 rows)
// wg = mi*48 + nf  (weight sharers co-located per XCD)
__global__ __launch_bounds__(256) void step_kernel(
    const unsigned short* __restrict__ xT,
    const unsigned short* __restrict__ Wb,
    unsigned short* __restrict__ S16,
    float* __restrict__ S32,
    int s)
{
    int wg = blockIdx.x;
    int mi = wg / 48;
    int nf = wg - mi * 48;
    int l  = nf >> 4;
    int ni = nf & 15;
    int t  = s - l;
    if (t < 0 || t >= TT) return;

    int tid  = threadIdx.x;
    int wave = tid >> 6;
    int lane = tid & 63;
    int mq = wave >> 1, nq = wave & 1;
    int m0 = mi * 64 + mq * 32;   // batch row base for this wave
    int n0 = ni * 64 + nq * 32;   // H col base (within layer)

    const unsigned short* Sc = S16 + (size_t)(s & 1) * (NL * BB * HH);
    unsigned short*       Sn = S16 + (size_t)((s + 1) & 1) * (NL * BB * HH);

    int ar = lane & 15;
    int kg = (lane >> 4) << 3;

    f32x4 a00 = {0.f, 0.f, 0.f, 0.f};
    f32x4 a01 = a00, a10 = a00, a11 = a00;

    // part 1: state_l @ W_res[l]^T   (K = H)
    {
        const unsigned short* A = Sc + (size_t)l * (BB * HH);
        const unsigned short* W = Wb + WRES_E + (size_t)l * (HH * HH);
        const unsigned short* Ar = A + (size_t)(m0 + ar) * HH + kg;
        const unsigned short* Br = W + (size_t)(n0 + ar) * HH + kg;
        gemm_part<HH>(Ar, Ar + 16 * HH, Br, Br + 16 * HH, a00, a01, a10, a11);
    }
    // part 0: cur @ W_in[l]^T
    if (l == 0) {
        const unsigned short* A = xT + (size_t)t * (BB * DIN);
        const unsigned short* W = Wb + WIN0_E;
        const unsigned short* Ar = A + (size_t)(m0 + ar) * DIN + kg;
        const unsigned short* Br = W + (size_t)(n0 + ar) * DIN + kg;
        gemm_part<DIN>(Ar, Ar + 16 * DIN, Br, Br + 16 * DIN, a00, a01, a10, a11);
    } else {
        const unsigned short* A = Sc + (size_t)(l - 1) * (BB * HH);
        const unsigned short* W = Wb + WIN12_E + (size_t)(l - 1) * (HH * HH);
        const unsigned short* Ar = A + (size_t)(m0 + ar) * HH + kg;
        const unsigned short* Br = W + (size_t)(n0 + ar) * HH + kg;
        gemm_part<HH>(Ar, Ar + 16 * HH, Br, Br + 16 * HH, a00, a01, a10, a11);
    }

    // epilogue: leaky update, fp32 master + bf16 broadcast copy
    // C/D layout (m89/m91): col = lane&15, row = (lane>>4)*4 + r
    int rb = (lane >> 4) << 2;
    int cc = lane & 15;
#pragma unroll
    for (int i = 0; i < 2; ++i) {
#pragma unroll
        for (int j = 0; j < 2; ++j) {
            f32x4 acc = (i == 0) ? ((j == 0) ? a00 : a01) : ((j == 0) ? a10 : a11);
#pragma unroll
            for (int r = 0; r < 4; ++r) {
                int b = m0 + i * 16 + rb + r;
                int h = n0 + j * 16 + cc;
                size_t idx = ((size_t)l * BB + b) * HH + h;
                float sold = S32[idx];
                float hnew = (1.0f - ALPHA) * sold + ALPHA * tanhf(acc[r]);
                S32[idx] = hnew;
                __hip_bfloat16 hb = __float2bfloat16(hnew);
                Sn[idx] = *(unsigned short*)&hb;
            }
        }
    }
}

// ---------------- readout ----------------
__global__ void out_kernel(const float* __restrict__ S32,
                           const float* __restrict__ w_out,
                           const float* __restrict__ b_out,
                           float* __restrict__ out)
{
    int b = blockIdx.x;
    int tid = threadIdx.x;
    float p = 0.f;
    for (int idx = tid; idx < NL * HH; idx += 256) {
        int l = idx >> 10;
        int h = idx & (HH - 1);
        p += S32[((size_t)l * BB + b) * HH + h] * w_out[idx];
    }
    __shared__ float red[256];
    red[tid] = p;
    __syncthreads();
    for (int off = 128; off > 0; off >>= 1) {
        if (tid < off) red[tid] += red[tid + off];
        __syncthreads();
    }
    if (tid == 0) out[b] = red[0] + b_out[0];
}

extern "C" void kernel_launch(void* const* d_in, const int* in_sizes, int n_in,
                              void* d_out, int out_size, void* d_ws, size_t ws_size,
                              hipStream_t stream)
{
    const float* x         = (const float*)d_in[0];
    const float* W_in0     = (const float*)d_in[1];
    const float* W_in_rest = (const float*)d_in[2];
    const float* W_res     = (const float*)d_in[3];
    const float* w_out     = (const float*)d_in[4];
    const float* b_out     = (const float*)d_in[5];

    char* ws = (char*)d_ws;
    unsigned short* xT  = (unsigned short*)(ws + XT_OFF);
    __hip_bfloat16* Wbh = (__hip_bfloat16*)(ws + WB_OFF);
    unsigned short* Wb  = (unsigned short*)(ws + WB_OFF);
    unsigned short* S16 = (unsigned short*)(ws + S16_OFF);
    float*          S32 = (float*)(ws + S32_OFF);

    convert_kernel<<<4096, 256, 0, stream>>>(W_in0, W_in_rest, W_res, Wbh);
    transpose_x_kernel<<<4096, 256, 0, stream>>>(x, xT);
    // zero both S16 buffers + S32 master (contiguous 6,291,456 bytes)
    hipMemsetAsync(ws + S16_OFF, 0, 6291456, stream);

    for (int s = 0; s < TT + NL - 1; ++s) {
        step_kernel<<<192, 256, 0, stream>>>(xT, Wb, S16, S32, s);
    }
    out_kernel<<<BB, 256, 0, stream>>>(S32, w_out, b_out, (float*)d_out);
}